// Round 1
// baseline (476.863 us; speedup 1.0000x reference)
//
#include <hip/hip_runtime.h>
#include <hip/hip_fp16.h>
#include <math.h>

typedef _Float16 half8  __attribute__((ext_vector_type(8)));
typedef _Float16 half4v __attribute__((ext_vector_type(4)));
typedef _Float16 half2v __attribute__((ext_vector_type(2)));
typedef __fp16   fp16x2v __attribute__((ext_vector_type(2)));
typedef float    f32x4  __attribute__((ext_vector_type(4)));
typedef float    f32x16 __attribute__((ext_vector_type(16)));

#define MFMA_F16 __builtin_amdgcn_mfma_f32_16x16x32_f16
#define MFMA32   __builtin_amdgcn_mfma_f32_32x32x16_f16

namespace {

constexpr int M_ROWS = 64;                   // rows per block (4 waves, 64x64 tile each)
// XOR-swizzled packed layouts (granule = 8 halves = 16 B):
//   Haddr(m,n) = m*256 + (((n>>3) ^ (m&7))<<3) + (n&7)         H: 32 KB
//   Paddr(m,k) = PE_OFF + m*64 + (((k>>3) ^ (m&7))<<3) + (k&7) PE: 8 KB
// R19: layer GEMMs moved to 32x32x16 MFMA (half the MFMA issues, +11% shape
// rate), A ring depth 4 (dist-3 covers L2 latency), B ring depth 3 (dist-2
// covers LDS latency). pe_pass/bias stores vectorized b16->b32: the 2.7e7
// SQ_LDS_BANK_CONFLICT was traced to 2-lanes-per-dword scalar b16 stores.
constexpr int H_OFF    = 0;                  // 16384 halves
constexpr int PE_OFF   = 16384;              // 4096 halves
constexpr int BIAS_OFF = 20480;              // 9*256 = 2304 halves
constexpr int LDS_HALVES = 22784;            // 45568 B -> 3 blocks/CU
constexpr size_t LDS_BYTES = (size_t)LDS_HALVES * sizeof(_Float16);

// Layer order: g1_0..g1_4, g2_0..g2_2, c_0, c_1, sig
constexpr int OFF_A[11] = {0,16384,81920,147456,212992,278528,360448,425984,491520,573440,577536};
constexpr int TOTAL_W   = 581632;   // fp16 elements in swizzled blob

struct Ptr11 { const float* p[11]; };

// Partial barrier: drain LDS only; register-targeted global loads stay in
// flight (consumers get per-use vmcnt waits from the compiler).
__device__ __forceinline__ void lds_barrier() {
  asm volatile("s_waitcnt lgkmcnt(0)\n\ts_barrier" ::: "memory");
}

// ---------------------------------------------------------------------------
// Weight pre-swizzle. 256-out layers (L<=8), 32x32x16 fragments:
//   blob[((kc*8 + nt)*64 + lane)*8 + j]
//     = W[remap(kc*16 + (lane>>5)*8 + j)][nt*32 + (lane&31)], 0 if pad.
// Heads (L=9,10), 16x16x32 fragments (unchanged):
//   blob[(kc*64 + lane)*8 + j] = W[kc*32 + (lane>>4)*8 + j][lane&15]
// ---------------------------------------------------------------------------
__global__ void prep_kernel(Ptr11 wp, _Float16* __restrict__ ws) {
  int tid = blockIdx.x * blockDim.x + threadIdx.x;
  if (tid >= TOTAL_W) return;
  int L = 0;
#pragma unroll
  for (int i = 1; i < 11; ++i) if (tid >= OFF_A[i]) L = i;
  int e    = tid - OFF_A[L];
  int j    = e & 7;
  int lane = (e >> 3) & 63;
  int rest = e >> 9;
  float v = 0.f;
  int idx;
  if (L <= 8) {
    int nt  = rest & 7;
    int kc  = rest >> 3;
    int hi  = lane >> 5, l31 = lane & 31;
    int kpad = kc * 16 + hi * 8 + j;
    int n    = nt * 32 + l31;
    int k;
    if      (L == 0) k = (kpad < 63) ? kpad : -1;                               // g1_0: din 63 pad->64
    else if (L == 5) k = (kpad < 64) ? ((kpad < 63) ? kpad : -1) : kpad - 1;    // g2_0: [pe_x 63|f1 256]
    else if (L == 8) k = (kpad < 64) ? ((kpad < 39) ? kpad : -1) : kpad - 25;   // c_0:  [pe_d 39|f2 256]
    else             k = kpad;                                                  // din 256 exact
    if (k >= 0) v = wp.p[L][k * 256 + n];
    idx = OFF_A[L] + ((kc * 8 + nt) * 64 + lane) * 8 + j;
  } else {
    int kc   = rest;
    int kpad = kc * 32 + (lane >> 4) * 8 + j;
    int n    = lane & 15;
    int dout = (L == 9) ? 3 : 1;
    if (n < dout) v = wp.p[L][kpad * dout + n];
    idx = OFF_A[L] + (kc * 64 + lane) * 8 + j;
  }
  ws[idx] = (_Float16)v;
}

// ---------------------------------------------------------------------------
// One 256-out linear layer on 32x32x16 MFMA. Wave cg: rows [0,64) x cols
// [cg*64,+64) as acc[ft][rt] (ft=feature 32-tile, rt=row 32-tile), 4 MFMA
// per K=16 step. D layout: n(data row)=lane&31, m(feature)=(reg&3)+
// 8*(reg>>2)+4*(lane>>5)  -> 4 consecutive regs = 4 consecutive features =
// one b64 store per granule. B read granule g=(kc<<1)|hi, XOR swizzle
// decomposes: ((kc^s7h)<<4) + ((hi^s7l)<<3) -> 4 precomputed base ptrs.
// A ring depth 4 (prefetch dist 3, covers L2), B ring depth 3 (dist 2).
// Bias pre-loaded into acc. Barriers: after K-loop (reads done), after
// epilogue (writes visible). All register indices compile-time (unrolled).
// ---------------------------------------------------------------------------
template <int PE_STEPS, int H_STEPS, bool RELU>
__device__ __forceinline__ void do_layer32(_Float16* lds,
                                           const _Float16* __restrict__ blob,
                                           int bias_idx, int cg, int lane) {
  constexpr int KS = PE_STEPS + H_STEPS;   // 4, 16, or 20 K=16 steps
  const int l31 = lane & 31;
  const int hi5 = lane >> 5;
  const int s7  = lane & 7;                // == row&7 for both rt tiles
  const int s7l = s7 & 1, s7h = s7 >> 1;

  half8 ar[4][2], br[3][2];
  const _Float16* ab = blob + cg * 1024 + lane * 8;

#define LOADA32(slot, S)                                                      \
  { _Pragma("unroll") for (int ft = 0; ft < 2; ++ft)                          \
      ar[slot][ft] = *(const half8*)(ab + (S) * 4096 + ft * 512); }

  LOADA32(0, 0)                      // issue earliest: cover bias-init below
  LOADA32(1, 1)
  LOADA32(2, 2)

  // Bias -> acc init (kills the epilogue add; bias depends on feature only:
  // m' = cg*64 + ft*32 + G*8 + hi5*4 + i  <->  acc[ft][*][G*4+i]).
  f32x16 acc[2][2];
  {
    const _Float16* bb_ = lds + BIAS_OFF + bias_idx * 256 + cg * 64 + hi5 * 4;
#pragma unroll
    for (int ft = 0; ft < 2; ++ft)
#pragma unroll
      for (int G = 0; G < 4; ++G) {
        half4v bh = *(const half4v*)(bb_ + ft * 32 + G * 8);
#pragma unroll
        for (int i = 0; i < 4; ++i) {
          float bf = (float)bh[i];
          acc[ft][0][G * 4 + i] = bf;
          acc[ft][1][G * 4 + i] = bf;
        }
      }
  }

  // Swizzled B base pointers (4 variants for the (kc&3)^s7h XOR).
  const _Float16* hx[4];
  const _Float16* px[4];
  {
    const _Float16* hb = lds + H_OFF  + l31 * 256 + ((hi5 ^ s7l) << 3);
    const _Float16* pb = lds + PE_OFF + l31 * 64  + ((hi5 ^ s7l) << 3);
#pragma unroll
    for (int t = 0; t < 4; ++t) {
      hx[t] = hb + ((t ^ s7h) << 4);
      px[t] = pb + ((t ^ s7h) << 4);
    }
  }

#define LOADB32(slot, S)                                                      \
  {                                                                           \
    if ((S) < PE_STEPS) {                                                     \
      _Pragma("unroll") for (int rt = 0; rt < 2; ++rt)                        \
          br[slot][rt] = *(const half8*)(px[(S) & 3] + rt * 2048);            \
    } else {                                                                  \
      const int kc_ = (S) - PE_STEPS;                                         \
      _Pragma("unroll") for (int rt = 0; rt < 2; ++rt)                        \
          br[slot][rt] =                                                      \
              *(const half8*)(hx[kc_ & 3] + ((kc_ >> 2) << 6) + rt * 8192);   \
    }                                                                         \
  }

#define DO_MFMA32(aslot, bslot)                                               \
  { _Pragma("unroll") for (int ft = 0; ft < 2; ++ft)                          \
      _Pragma("unroll") for (int rt = 0; rt < 2; ++rt)                        \
          acc[ft][rt] = MFMA32(ar[aslot][ft], br[bslot][rt], acc[ft][rt], 0, 0, 0); }

  LOADB32(0, 0)
  LOADB32(1, 1)
#pragma unroll
  for (int kk = 0; kk < KS; ++kk) {
    if (kk + 2 < KS) LOADB32((kk + 2) % 3, kk + 2)
    if (kk + 3 < KS) LOADA32((kk + 3) & 3, kk + 3)
    DO_MFMA32(kk & 3, kk % 3)
  }
#undef LOADA32
#undef LOADB32
#undef DO_MFMA32

  lds_barrier();   // all waves done READING H/PE before anyone overwrites H

  // Epilogue: granule X = ft*4+G, write at n'*256 + cg*64 +
  // ((X^s7)<<3) + hi5*4, rt adds 8192. 4 regs -> 2 cvt_pkrtz -> one b64.
  _Float16* wb = lds + H_OFF + l31 * 256 + cg * 64 + hi5 * 4;
  _Float16* wq[8];
#pragma unroll
  for (int X = 0; X < 8; ++X) wq[X] = wb + ((X ^ s7) << 3);
#pragma unroll
  for (int ft = 0; ft < 2; ++ft)
#pragma unroll
    for (int rt = 0; rt < 2; ++rt)
#pragma unroll
      for (int G = 0; G < 4; ++G) {
        float v0 = acc[ft][rt][G * 4 + 0];
        float v1 = acc[ft][rt][G * 4 + 1];
        float v2 = acc[ft][rt][G * 4 + 2];
        float v3 = acc[ft][rt][G * 4 + 3];
        if (RELU) {
          v0 = fmaxf(v0, 0.f); v1 = fmaxf(v1, 0.f);
          v2 = fmaxf(v2, 0.f); v3 = fmaxf(v3, 0.f);
        }
        fp16x2v lo  = __builtin_amdgcn_cvt_pkrtz(v0, v1);
        fp16x2v hi2 = __builtin_amdgcn_cvt_pkrtz(v2, v3);
        uint2 pk = { __builtin_bit_cast(unsigned int, lo),
                     __builtin_bit_cast(unsigned int, hi2) };
        *(uint2*)(wq[ft * 4 + G] + rt * 8192) = pk;
      }
  lds_barrier();   // writes visible to all waves
}

// Head (sig / c_1): 16x16x32 path, K=256 over H; wave w rows [w*16,+16).
__device__ __forceinline__ f32x4 head_mt(const _Float16* lds,
                                         const _Float16* __restrict__ blob,
                                         int w, int lane) {
  const int l15  = lane & 15;
  const int quad = lane >> 4;
  const int s7   = l15 & 7;
  const int c1   = s7 >> 2;
  const int q3   = (quad ^ (s7 & 3));
  const _Float16* hb = lds + H_OFF + (w * 16 + l15) * 256 + q3 * 8;
  f32x4 res = (f32x4)0.f;
#pragma unroll
  for (int kc = 0; kc < 8; ++kc) {
    half8 a = *(const half8*)(blob + (kc * 64 + lane) * 8);
    half8 b = *(const half8*)(hb + ((kc ^ c1) << 5));
    res = MFMA_F16(a, b, res, 0, 0, 0);
  }
  return res;
}

__device__ __forceinline__ void pe_classify(int f, int nfeat, int& mode, int& c,
                                            int& use_cos, float& freq) {
  mode = 2; c = 0; use_cos = 0; freq = 0.f;
  if (f < 3) { mode = 0; c = f; }
  else if (f < nfeat) {
    int g = f - 3, li = g / 6, rem = g - li * 6;
    use_cos = (rem >= 3); c = use_cos ? rem - 3 : rem;
    freq = (float)(1 << li); mode = 1;
  }
}

// Positional encoding, R19: each thread owns a FEATURE PAIR (2fp, 2fp+1) for
// 8 rows -> one aligned b32 store per row (was 16 scalar b16 stores: 2 lanes
// per dword = the SQ_LDS_BANK_CONFLICT source). r&7 == rb: swizzle key is
// loop-invariant per thread.
__device__ __forceinline__ void pe_pass(_Float16* lds, const float* __restrict__ src,
                                        int row0, int tid, int nfeat) {
  const int fp = tid & 31;           // feature pair 0..31
  const int rb = tid >> 5;           // row base 0..7
  int m0, c0, u0; float q0;
  int m1, c1_, u1; float q1;
  pe_classify(fp * 2,     nfeat, m0, c0,  u0, q0);
  pe_classify(fp * 2 + 1, nfeat, m1, c1_, u1, q1);
  const int swz = (((fp >> 2) ^ rb) << 3) | ((fp & 3) * 2);
#pragma unroll
  for (int t = 0; t < 8; ++t) {
    int r = t * 8 + rb;
    float v0 = 0.f, v1 = 0.f;
    if (m0 == 0) v0 = src[(row0 + r) * 3 + c0];
    else if (m0 == 1) {
      float a = src[(row0 + r) * 3 + c0] * q0;
      v0 = u0 ? __cosf(a) : __sinf(a);
    }
    if (m1 == 0) v1 = src[(row0 + r) * 3 + c1_];
    else if (m1 == 1) {
      float a = src[(row0 + r) * 3 + c1_] * q1;
      v1 = u1 ? __cosf(a) : __sinf(a);
    }
    half2v hv = { (_Float16)v0, (_Float16)v1 };
    *(half2v*)(lds + PE_OFF + r * 64 + swz) = hv;
  }
}

__global__ __launch_bounds__(256, 3) void nerf_kernel(
    const _Float16* __restrict__ ws, const float* __restrict__ x,
    const float* __restrict__ dirp, Ptr11 bp, float* __restrict__ out) {
  extern __shared__ _Float16 lds[];
  const int tid  = threadIdx.x;
  const int lane = tid & 63;
  const int w    = tid >> 6;       // wave 0..3 (= col-group cg)
  const int l15  = lane & 15;
  const int quad = lane >> 4;
  const int row0 = blockIdx.x * M_ROWS;

  // ---- pe_x -> PE buffer; biases -> LDS (f16, b32 stores, once) ----
  pe_pass(lds, x, row0, tid, 63);
  for (int i = tid; i < 1152; i += 256) {       // 9*256 halves as 1152 dwords
    int L = i >> 7, e2 = (i & 127) * 2;
    half2v hv = { (_Float16)bp.p[L][e2], (_Float16)bp.p[L][e2 + 1] };
    *(half2v*)(lds + BIAS_OFF + L * 256 + e2) = hv;
  }
  lds_barrier();

  // ---- G1: 63->256, 256->256 x4 (ReLU on all but last) ----
  do_layer32<4, 0,  true >(lds, ws + OFF_A[0], 0, w, lane);
  do_layer32<0, 16, true >(lds, ws + OFF_A[1], 1, w, lane);
  do_layer32<0, 16, true >(lds, ws + OFF_A[2], 2, w, lane);
  do_layer32<0, 16, true >(lds, ws + OFF_A[3], 3, w, lane);
  do_layer32<0, 16, false>(lds, ws + OFF_A[4], 4, w, lane);  // f1
  // ---- G2: [pe_x|f1] -> 256, 256->256, 256->256 (no ReLU on last) ----
  do_layer32<4, 16, true >(lds, ws + OFF_A[5], 5, w, lane);  // pe_x last use
  do_layer32<0, 16, true >(lds, ws + OFF_A[6], 6, w, lane);
  do_layer32<0, 16, false>(lds, ws + OFF_A[7], 7, w, lane);  // f2

  // ---- sigma head reads f2; pe_d overwrites PE (pe_x dead) ----
  f32x4 sa = head_mt(lds, ws + OFF_A[10], w, lane);
  float sigv = sa[0] + bp.p[10][0];   // valid in quad==0 lanes
  pe_pass(lds, dirp, row0, tid, 39);
  lds_barrier();     // pe_d visible before c_0; sig H-reads done

  // ---- color: c_0 [pe_d|f2] -> H (ReLU), c_1 reads H ----
  do_layer32<4, 16, true>(lds, ws + OFF_A[8], 8, w, lane);
  f32x4 ca = head_mt(lds, ws + OFF_A[9], w, lane);
  if (quad == 0) {
    f32x4 o = { ca[0] + bp.p[9][0], ca[1] + bp.p[9][1], ca[2] + bp.p[9][2], sigv };
    *(f32x4*)(out + (size_t)(row0 + w * 16 + l15) * 4) = o;
  }
}

}  // namespace

extern "C" void kernel_launch(void* const* d_in, const int* in_sizes, int n_in,
                              void* d_out, int out_size, void* d_ws, size_t ws_size,
                              hipStream_t stream) {
  const float* x   = (const float*)d_in[0];
  const float* dir = (const float*)d_in[1];
  Ptr11 wp, bp;
  for (int i = 0; i < 11; ++i) {
    wp.p[i] = (const float*)d_in[2 + 2 * i];
    bp.p[i] = (const float*)d_in[3 + 2 * i];
  }
  _Float16* ws = (_Float16*)d_ws;
  float* out = (float*)d_out;

  (void)hipFuncSetAttribute((const void*)nerf_kernel,
                            hipFuncAttributeMaxDynamicSharedMemorySize,
                            (int)LDS_BYTES);

  prep_kernel<<<(TOTAL_W + 255) / 256, 256, 0, stream>>>(wp, ws);
  nerf_kernel<<<262144 / M_ROWS, 256, LDS_BYTES, stream>>>(ws, x, dir, bp, out);
}